// Round 6
// baseline (722.985 us; speedup 1.0000x reference)
//
#include <hip/hip_runtime.h>
#include <math.h>

#define NFEAT 128

// edge record: .x = col index (int), .y = dis[src]*w (float bits); dis[dst] folded into epilogue
typedef int2 EdgeRec;

// ---------------- CSR build ----------------

__global__ void k_init(unsigned long long* packed, int N) {
  int i = blockIdx.x * blockDim.x + threadIdx.x;
  if (i < N) packed[i] = 0ull;
}

// ONE u64 atomic per edge: count in bits[40..], fixed-point (2^-32) weight sum in bits[0..40).
// Returned old count = this edge's slot offset within its row.
__global__ void k_count64(const int* __restrict__ dst, const float* __restrict__ ew,
                          unsigned long long* packed, int* off, int E) {
  int e = blockIdx.x * blockDim.x + threadIdx.x;
  if (e < E) {
    unsigned long long add = (1ull << 40) | (unsigned long long)(ew[e] * 4294967296.0f);
    unsigned long long old = atomicAdd(&packed[dst[e]], add);
    off[e] = (int)(old >> 40);
  }
}

__global__ void k_dis(const unsigned long long* __restrict__ packed, float* dis, int N) {
  int i = blockIdx.x * blockDim.x + threadIdx.x;
  if (i < N) {
    double s = (double)(packed[i] & ((1ull << 40) - 1)) * 2.3283064365386963e-10;  // /2^32
    float dg = 1.0f + (float)s;  // + self-loop weight
    dis[i] = 1.0f / sqrtf(dg);
  }
}

// ---- 3-phase parallel exclusive scan of (cnt[i]+1) -> rowptr, 1024 elems/block ----

__global__ __launch_bounds__(256) void k_scan1(const unsigned long long* __restrict__ packed,
                                               int* bsum, int N) {
  __shared__ int ls[256];
  int b = blockIdx.x, t = threadIdx.x;
  int base = b * 1024 + t * 4;
  int s = 0;
#pragma unroll
  for (int j = 0; j < 4; j++) { int i = base + j; if (i < N) s += (int)(packed[i] >> 40) + 1; }
  ls[t] = s;
  __syncthreads();
  for (int off = 128; off > 0; off >>= 1) {
    if (t < off) ls[t] += ls[t + off];
    __syncthreads();
  }
  if (t == 0) bsum[b] = ls[0];
}

__global__ __launch_bounds__(1024) void k_scan2(int* bsum, int SB) {
  __shared__ int ls[1024];
  int t = threadIdx.x;
  int v = (t < SB) ? bsum[t] : 0;
  ls[t] = v;
  __syncthreads();
  for (int off = 1; off < 1024; off <<= 1) {
    int u = (t >= off) ? ls[t - off] : 0;
    __syncthreads();
    ls[t] += u;
    __syncthreads();
  }
  if (t < SB) bsum[t] = ls[t] - v;  // exclusive
}

__global__ __launch_bounds__(256) void k_scan3(const unsigned long long* __restrict__ packed,
                                               const int* __restrict__ bsum,
                                               int* rowptr, int N, int M) {
  __shared__ int ls[256];
  int b = blockIdx.x, t = threadIdx.x;
  int base = b * 1024 + t * 4;
  int v[4]; int s = 0;
#pragma unroll
  for (int j = 0; j < 4; j++) {
    int i = base + j;
    v[j] = (i < N) ? (int)(packed[i] >> 40) + 1 : 0;
    s += v[j];
  }
  ls[t] = s;
  __syncthreads();
  for (int off = 1; off < 256; off <<= 1) {
    int u = (t >= off) ? ls[t - off] : 0;
    __syncthreads();
    ls[t] += u;
    __syncthreads();
  }
  int run = bsum[b] + ls[t] - s;
#pragma unroll
  for (int j = 0; j < 4; j++) { int i = base + j; if (i < N) { rowptr[i] = run; run += v[j]; } }
  if (b == 0 && t == 0) rowptr[N] = M;
}

__global__ void k_selfloop(const int* __restrict__ rowptr, const float* __restrict__ dis,
                           EdgeRec* ep, int N) {
  int i = blockIdx.x * blockDim.x + threadIdx.x;
  if (i < N) {
    EdgeRec r; r.x = i; r.y = __float_as_int(dis[i]);  // dis[i]*1.0; *dis[i] applied in epilogue
    ep[rowptr[i]] = r;
  }
}

// no atomics: slot = rowptr[dst] + 1 + off[e]
__global__ void k_fill(const int* __restrict__ src, const int* __restrict__ dst,
                       const float* __restrict__ ew, const float* __restrict__ dis,
                       const int* __restrict__ rowptr, const int* __restrict__ off,
                       EdgeRec* ep, int E) {
  int e = blockIdx.x * blockDim.x + threadIdx.x;
  if (e < E) {
    int s = src[e], d = dst[e];
    int p = rowptr[d] + 1 + off[e];
    EdgeRec r; r.x = s; r.y = __float_as_int(dis[s] * ew[e]);
    ep[p] = r;
  }
}

// ---------------- fused aggregate + transform ----------------
// Uses agg(x @ W) == agg(x) @ W (aggregation is linear).
// Per wave, per node:
//   1) v = dis[node] * sum_e w_e * Hin[col_e]   (gather-agg, half-wave float4 split)
//   2) o[j] = sum_k v[k] * W[k][j] for lane-owned cols (2*lane, 2*lane+1); W in LDS,
//      v broadcast from registers via __shfl.
//   3) FINAL=false: store relu(o + b) as the node's 128-wide hidden row.
//      FINAL=true:  z[node] = dot(relu(o + b), W3)  (h2 never materialized).
// The GEMM's VALU/LDS work hides under the fabric-bound gather stalls.
// 768 threads, 64 KB LDS -> 2 blocks/CU = 24 waves/CU; launch_bounds(768,6) caps VGPR at 85.

template <bool FINAL>
__global__ __launch_bounds__(768, 6) void k_fused(const float* __restrict__ Hin,
                                                  const int* __restrict__ rowptr,
                                                  const EdgeRec* __restrict__ ep,
                                                  const float* __restrict__ dis,
                                                  const float* __restrict__ Wm,
                                                  const float* __restrict__ bias,
                                                  const float* __restrict__ W3,
                                                  float* __restrict__ out, int N) {
  __shared__ float sW[128 * 128];  // 64 KB
  int t = threadIdx.x;
  int wave = __builtin_amdgcn_readfirstlane(t >> 6);  // 0..11
  int lane = t & 63;
  int half = lane >> 5;
  int l32  = lane & 31;
  {
    const float4* W4 = (const float4*)Wm;
    float4* sW4 = (float4*)sW;
    for (int i = t; i < 4096; i += 768) sW4[i] = W4[i];
  }
  __syncthreads();

  int gw = blockIdx.x * 12 + wave;
  for (int node = gw; node < N; node += 6144) {
    int beg = rowptr[node], end = rowptr[node + 1];
    int last = end - 1;
    int pmax = (end - beg + 1) >> 1;  // pair-slots; slot p covers edge beg+2p+half
    int ebase = beg + half;

    float4 acc = make_float4(0.f, 0.f, 0.f, 0.f);
    EdgeRec cur[4], nxt[4];
#pragma unroll
    for (int j = 0; j < 4; j++) {
      int e = ebase + 2 * j;
      cur[j] = ep[e <= last ? e : last];
    }
    for (int p = 0; p < pmax; p += 4) {
      int nbase = ebase + 2 * (p + 4);
#pragma unroll
      for (int j = 0; j < 4; j++) {
        int e = nbase + 2 * j;
        nxt[j] = ep[e <= last ? e : last];
      }
      float4 h[4];
#pragma unroll
      for (int j = 0; j < 4; j++)
        h[j] = *(const float4*)(Hin + (size_t)cur[j].x * 128 + 4 * l32);
#pragma unroll
      for (int j = 0; j < 4; j++) {
        int e = ebase + 2 * (p + j);
        float w = (e <= last) ? __int_as_float(cur[j].y) : 0.f;
        acc.x = fmaf(w, h[j].x, acc.x);
        acc.y = fmaf(w, h[j].y, acc.y);
        acc.z = fmaf(w, h[j].z, acc.z);
        acc.w = fmaf(w, h[j].w, acc.w);
      }
#pragma unroll
      for (int j = 0; j < 4; j++) cur[j] = nxt[j];
    }
    // combine halves (symmetric add -> all 64 lanes hold full sum)
    acc.x += __shfl_xor(acc.x, 32, 64);
    acc.y += __shfl_xor(acc.y, 32, 64);
    acc.z += __shfl_xor(acc.z, 32, 64);
    acc.w += __shfl_xor(acc.w, 32, 64);
    float ds = dis[node];
    acc.x *= ds; acc.y *= ds; acc.z *= ds; acc.w *= ds;
    // now lane l32 (both halves) holds v[4*l32 .. 4*l32+3]

    // per-wave GEMM: o = v @ W, lane owns output cols (2*lane, 2*lane+1)
    float2 o = make_float2(0.f, 0.f);
#pragma unroll 4
    for (int kb = 0; kb < 32; kb++) {
      float vx = __shfl(acc.x, kb, 64);
      float vy = __shfl(acc.y, kb, 64);
      float vz = __shfl(acc.z, kb, 64);
      float vw = __shfl(acc.w, kb, 64);
      float2 w0 = *(const float2*)(sW + (4 * kb + 0) * 128 + 2 * lane);
      float2 w1 = *(const float2*)(sW + (4 * kb + 1) * 128 + 2 * lane);
      float2 w2 = *(const float2*)(sW + (4 * kb + 2) * 128 + 2 * lane);
      float2 w3 = *(const float2*)(sW + (4 * kb + 3) * 128 + 2 * lane);
      o.x = fmaf(vx, w0.x, o.x); o.y = fmaf(vx, w0.y, o.y);
      o.x = fmaf(vy, w1.x, o.x); o.y = fmaf(vy, w1.y, o.y);
      o.x = fmaf(vz, w2.x, o.x); o.y = fmaf(vz, w2.y, o.y);
      o.x = fmaf(vw, w3.x, o.x); o.y = fmaf(vw, w3.y, o.y);
    }
    float2 bv = *(const float2*)(bias + 2 * lane);
    o.x += bv.x; o.x = o.x > 0.f ? o.x : 0.f;
    o.y += bv.y; o.y = o.y > 0.f ? o.y : 0.f;

    if (FINAL) {
      float2 w3v = *(const float2*)(W3 + 2 * lane);
      float pdot = o.x * w3v.x + o.y * w3v.y;
#pragma unroll
      for (int off = 32; off > 0; off >>= 1) pdot += __shfl_down(pdot, off, 64);
      if (lane == 0) out[node] = pdot;
    } else {
      *(float2*)(out + (size_t)node * 128 + 2 * lane) = o;
    }
  }
}

// ---------------- scalar aggregate + bias + relu ----------------

__global__ void k_aggs(const float* __restrict__ z, const int* __restrict__ rowptr,
                       const EdgeRec* __restrict__ ep, const float* __restrict__ dis,
                       const float* __restrict__ b3, float* __restrict__ out, int N) {
  int n = blockIdx.x * blockDim.x + threadIdx.x;
  if (n >= N) return;
  float acc = 0.f;
  int end = rowptr[n + 1];
  for (int e = rowptr[n]; e < end; e++) {
    EdgeRec p = ep[e];
    acc = fmaf(__int_as_float(p.y), z[p.x], acc);
  }
  acc = fmaf(dis[n], acc, b3[0]);
  out[n] = acc > 0.f ? acc : 0.f;
}

// ---------------- launch ----------------

extern "C" void kernel_launch(void* const* d_in, const int* in_sizes, int n_in,
                              void* d_out, int out_size, void* d_ws, size_t ws_size,
                              hipStream_t stream) {
  const float* x  = (const float*)d_in[0];
  const int*   ei = (const int*)d_in[1];
  const float* ew = (const float*)d_in[2];
  const float* W1 = (const float*)d_in[3];
  const float* b1 = (const float*)d_in[4];
  const float* W2 = (const float*)d_in[5];
  const float* b2 = (const float*)d_in[6];
  const float* W3 = (const float*)d_in[7];
  const float* b3 = (const float*)d_in[8];
  int N = in_sizes[0] / NFEAT;
  int E = in_sizes[2];
  int M = E + N;
  const int* srcp = ei;
  const int* dstp = ei + E;

  char* p = (char*)d_ws;
  auto carve = [&](size_t bytes) -> void* {
    void* r = (void*)p;
    p += (bytes + 511) & ~(size_t)511;
    return r;
  };
  unsigned long long* packed = (unsigned long long*)carve(sizeof(unsigned long long) * N);
  int*     off    = (int*)  carve(sizeof(int) * E);
  int*     rowptr = (int*)  carve(sizeof(int) * (N + 1));
  float*   dis    = (float*)carve(sizeof(float) * N);
  int*     bsum   = (int*)  carve(sizeof(int) * 1024);
  EdgeRec* ep     = (EdgeRec*)carve(sizeof(EdgeRec) * M);
  float*   t1     = (float*)carve(sizeof(float) * (size_t)N * NFEAT);
  float*   z      = (float*)carve(sizeof(float) * N);

  int gN = (N + 255) / 256, gE = (E + 255) / 256;
  int SB = (N + 1023) / 1024;

  k_init<<<gN, 256, 0, stream>>>(packed, N);
  k_count64<<<gE, 256, 0, stream>>>(dstp, ew, packed, off, E);
  k_dis<<<gN, 256, 0, stream>>>(packed, dis, N);
  k_scan1<<<SB, 256, 0, stream>>>(packed, bsum, N);
  k_scan2<<<1, 1024, 0, stream>>>(bsum, SB);
  k_scan3<<<SB, 256, 0, stream>>>(packed, bsum, rowptr, N, M);
  k_selfloop<<<gN, 256, 0, stream>>>(rowptr, dis, ep, N);
  k_fill<<<gE, 256, 0, stream>>>(srcp, dstp, ew, dis, rowptr, off, ep, E);

  // layer 1: h1 = relu(agg(x) @ W1 + b1)
  k_fused<false><<<512, 768, 0, stream>>>(x, rowptr, ep, dis, W1, b1, nullptr, t1, N);
  // layer 2+3a: z = relu(agg(h1) @ W2 + b2) . W3   (h2 never materialized)
  k_fused<true><<<512, 768, 0, stream>>>(t1, rowptr, ep, dis, W2, b2, W3, z, N);
  // layer 3b: out = relu(dis * agg(z) + b3)
  k_aggs<<<gN, 256, 0, stream>>>(z, rowptr, ep, dis, b3, (float*)d_out, N);
}

// Round 7
// 636.124 us; speedup vs baseline: 1.1365x; 1.1365x over previous
//
#include <hip/hip_runtime.h>
#include <math.h>

#define NFEAT 128

// edge record: .x = col index (int), .y = dis[src]*w (float bits); dis[dst] folded into epilogue
typedef int2 EdgeRec;

// ---------------- CSR build ----------------

__global__ void k_init(unsigned long long* packed, int N) {
  int i = blockIdx.x * blockDim.x + threadIdx.x;
  if (i < N) packed[i] = 0ull;
}

// ONE u64 atomic per edge: count in bits[40..], fixed-point (2^-32) weight sum in bits[0..40).
// Returned old count = this edge's slot offset within its row.
__global__ void k_count64(const int* __restrict__ dst, const float* __restrict__ ew,
                          unsigned long long* packed, int* off, int E) {
  int e = blockIdx.x * blockDim.x + threadIdx.x;
  if (e < E) {
    unsigned long long add = (1ull << 40) | (unsigned long long)(ew[e] * 4294967296.0f);
    unsigned long long old = atomicAdd(&packed[dst[e]], add);
    off[e] = (int)(old >> 40);
  }
}

__global__ void k_dis(const unsigned long long* __restrict__ packed, float* dis, int N) {
  int i = blockIdx.x * blockDim.x + threadIdx.x;
  if (i < N) {
    double s = (double)(packed[i] & ((1ull << 40) - 1)) * 2.3283064365386963e-10;  // /2^32
    float dg = 1.0f + (float)s;  // + self-loop weight
    dis[i] = 1.0f / sqrtf(dg);
  }
}

// ---- 3-phase parallel exclusive scan of (cnt[i]+1) -> rowptr, 1024 elems/block ----

__global__ __launch_bounds__(256) void k_scan1(const unsigned long long* __restrict__ packed,
                                               int* bsum, int N) {
  __shared__ int ls[256];
  int b = blockIdx.x, t = threadIdx.x;
  int base = b * 1024 + t * 4;
  int s = 0;
#pragma unroll
  for (int j = 0; j < 4; j++) { int i = base + j; if (i < N) s += (int)(packed[i] >> 40) + 1; }
  ls[t] = s;
  __syncthreads();
  for (int off = 128; off > 0; off >>= 1) {
    if (t < off) ls[t] += ls[t + off];
    __syncthreads();
  }
  if (t == 0) bsum[b] = ls[0];
}

__global__ __launch_bounds__(1024) void k_scan2(int* bsum, int SB) {
  __shared__ int ls[1024];
  int t = threadIdx.x;
  int v = (t < SB) ? bsum[t] : 0;
  ls[t] = v;
  __syncthreads();
  for (int off = 1; off < 1024; off <<= 1) {
    int u = (t >= off) ? ls[t - off] : 0;
    __syncthreads();
    ls[t] += u;
    __syncthreads();
  }
  if (t < SB) bsum[t] = ls[t] - v;  // exclusive
}

__global__ __launch_bounds__(256) void k_scan3(const unsigned long long* __restrict__ packed,
                                               const int* __restrict__ bsum,
                                               int* rowptr, int N, int M) {
  __shared__ int ls[256];
  int b = blockIdx.x, t = threadIdx.x;
  int base = b * 1024 + t * 4;
  int v[4]; int s = 0;
#pragma unroll
  for (int j = 0; j < 4; j++) {
    int i = base + j;
    v[j] = (i < N) ? (int)(packed[i] >> 40) + 1 : 0;
    s += v[j];
  }
  ls[t] = s;
  __syncthreads();
  for (int off = 1; off < 256; off <<= 1) {
    int u = (t >= off) ? ls[t - off] : 0;
    __syncthreads();
    ls[t] += u;
    __syncthreads();
  }
  int run = bsum[b] + ls[t] - s;
#pragma unroll
  for (int j = 0; j < 4; j++) { int i = base + j; if (i < N) { rowptr[i] = run; run += v[j]; } }
  if (b == 0 && t == 0) rowptr[N] = M;
}

__global__ void k_selfloop(const int* __restrict__ rowptr, const float* __restrict__ dis,
                           EdgeRec* ep, int N) {
  int i = blockIdx.x * blockDim.x + threadIdx.x;
  if (i < N) {
    EdgeRec r; r.x = i; r.y = __float_as_int(dis[i]);  // dis[i]*1.0; *dis[i] applied in epilogue
    ep[rowptr[i]] = r;
  }
}

// no atomics: slot = rowptr[dst] + 1 + off[e]
__global__ void k_fill(const int* __restrict__ src, const int* __restrict__ dst,
                       const float* __restrict__ ew, const float* __restrict__ dis,
                       const int* __restrict__ rowptr, const int* __restrict__ off,
                       EdgeRec* ep, int E) {
  int e = blockIdx.x * blockDim.x + threadIdx.x;
  if (e < E) {
    int s = src[e], d = dst[e];
    int p = rowptr[d] + 1 + off[e];
    EdgeRec r; r.x = s; r.y = __float_as_int(dis[s] * ew[e]);
    ep[p] = r;
  }
}

// ---------------- dense GEMM: Y[N,128] = X[N,128] @ W[128,128] ----------------
// W (64 KB) + X tile double-buffer (2 x 32 KB) all in LDS -> 128 KB, 1 block/CU,
// 512 threads (8 waves). Software pipeline: global loads for tile t+1 issue into
// VGPRs BEFORE the compute of tile t; the ds_write (which forces the vmcnt wait)
// happens only AFTER the ~8192-cycle compute phase, so HBM latency is fully hidden.
// Inner loop: x via LDS broadcast reads (wave-uniform addr), w via b64 reads
// (even bank spread = minimum LDS cycles) -> VALU-issue-bound.

__global__ __launch_bounds__(512) void k_gemm128(const float* __restrict__ X,
                                                 const float* __restrict__ W,
                                                 float* __restrict__ Y,
                                                 int N, int numTiles) {
  __shared__ float sW[128 * 128];      // 64 KB
  __shared__ float sX[2][64 * 128];    // 2 x 32 KB
  int t = threadIdx.x;
  int wave = __builtin_amdgcn_readfirstlane(t >> 6);  // 0..7
  int lane = t & 63;

  {
    const float4* W4 = (const float4*)W;
    float4* sW4 = (float4*)sW;
    for (int i = t; i < 4096; i += 512) sW4[i] = W4[i];
  }

  const float4* X4 = (const float4*)X;
  int gmax = N * 32 - 1;  // last valid float4 index in X

  // prologue: stage tile blockIdx.x into buf 0
  float4 stg[4];
  {
    int gbase = blockIdx.x * 2048;
#pragma unroll
    for (int j = 0; j < 4; j++) {
      int g = gbase + t + 512 * j;
      stg[j] = X4[g <= gmax ? g : gmax];
    }
    float4* sX4 = (float4*)sX[0];
#pragma unroll
    for (int j = 0; j < 4; j++) sX4[t + 512 * j] = stg[j];
  }
  __syncthreads();

  int buf = 0;
  for (int tile = blockIdx.x; tile < numTiles; tile += gridDim.x) {
    int nt = tile + gridDim.x;
    bool hasNext = nt < numTiles;
    if (hasNext) {
      int gbase = nt * 2048;
#pragma unroll
      for (int j = 0; j < 4; j++) {
        int g = gbase + t + 512 * j;
        stg[j] = X4[g <= gmax ? g : gmax];
      }
    }

    // compute from sX[buf]: wave owns rows wave*8..+7, lane owns cols (2*lane, 2*lane+1)
    const float* xb = &sX[buf][wave * 8 * 128];
    float2 acc[8];
#pragma unroll
    for (int r = 0; r < 8; r++) acc[r] = make_float2(0.f, 0.f);

    for (int k = 0; k < 128; k += 4) {
      float4 xv[8];
#pragma unroll
      for (int r = 0; r < 8; r++) xv[r] = *(const float4*)(xb + r * 128 + k);  // broadcast
#pragma unroll
      for (int kk = 0; kk < 4; kk++) {
        float2 wv = *(const float2*)(sW + (k + kk) * 128 + 2 * lane);
#pragma unroll
        for (int r = 0; r < 8; r++) {
          float xs = (&xv[r].x)[kk];
          acc[r].x = fmaf(xs, wv.x, acc[r].x);
          acc[r].y = fmaf(xs, wv.y, acc[r].y);
        }
      }
    }

    // store Y
    int rowBase = tile * 64 + wave * 8;
#pragma unroll
    for (int r = 0; r < 8; r++) {
      int row = rowBase + r;
      if (row < N)
        *(float2*)(Y + (size_t)row * 128 + 2 * lane) = acc[r];
    }

    __syncthreads();  // all waves done reading sX[buf^1] (prev iter) & sX[buf] (this iter)
    if (hasNext) {
      float4* sX4 = (float4*)sX[buf ^ 1];
#pragma unroll
      for (int j = 0; j < 4; j++) sX4[t + 512 * j] = stg[j];  // vmcnt wait lands here
    }
    __syncthreads();  // next buffer ready
    buf ^= 1;
  }
}

// ---------------- sparse aggregate, 128-wide: Out = relu(dis[n]*agg + b) ----------------
// One wave per dst node. Half-wave split: lanes 0-31 take even edge slots, 32-63 odd.
// Lane gathers float4 (features 4*l32..+3); ep records for next group prefetched.

__global__ __launch_bounds__(256) void k_agg128(const float* __restrict__ H,
                                                const int* __restrict__ rowptr,
                                                const EdgeRec* __restrict__ ep,
                                                const float* __restrict__ dis,
                                                const float* __restrict__ bias,
                                                float* __restrict__ Out, int N) {
  int wave = __builtin_amdgcn_readfirstlane(threadIdx.x >> 6);
  int lane = threadIdx.x & 63;
  int half = lane >> 5;
  int l32  = lane & 31;
  int node = blockIdx.x * 4 + wave;
  if (node >= N) return;
  int beg = rowptr[node], end = rowptr[node + 1];
  int last = end - 1;
  int pmax = (end - beg + 1) >> 1;  // pair-slots; slot p covers edge beg+2p+half
  int ebase = beg + half;

  float4 acc = make_float4(0.f, 0.f, 0.f, 0.f);
  EdgeRec cur[4], nxt[4];
#pragma unroll
  for (int j = 0; j < 4; j++) {
    int e = ebase + 2 * j;
    cur[j] = ep[e <= last ? e : last];
  }
  for (int p = 0; p < pmax; p += 4) {
    int nbase = ebase + 2 * (p + 4);
#pragma unroll
    for (int j = 0; j < 4; j++) {
      int e = nbase + 2 * j;
      nxt[j] = ep[e <= last ? e : last];
    }
    float4 h[4];
#pragma unroll
    for (int j = 0; j < 4; j++)
      h[j] = *(const float4*)(H + (size_t)cur[j].x * 128 + 4 * l32);
#pragma unroll
    for (int j = 0; j < 4; j++) {
      int e = ebase + 2 * (p + j);
      float w = (e <= last) ? __int_as_float(cur[j].y) : 0.f;
      acc.x = fmaf(w, h[j].x, acc.x);
      acc.y = fmaf(w, h[j].y, acc.y);
      acc.z = fmaf(w, h[j].z, acc.z);
      acc.w = fmaf(w, h[j].w, acc.w);
    }
#pragma unroll
    for (int j = 0; j < 4; j++) cur[j] = nxt[j];
  }
  // combine halves
  acc.x += __shfl_xor(acc.x, 32, 64);
  acc.y += __shfl_xor(acc.y, 32, 64);
  acc.z += __shfl_xor(acc.z, 32, 64);
  acc.w += __shfl_xor(acc.w, 32, 64);
  if (half == 0) {
    float ds = dis[node];
    float4 bv = *(const float4*)(bias + 4 * l32);
    float4 o;
    o.x = fmaf(ds, acc.x, bv.x); o.x = o.x > 0.f ? o.x : 0.f;
    o.y = fmaf(ds, acc.y, bv.y); o.y = o.y > 0.f ? o.y : 0.f;
    o.z = fmaf(ds, acc.z, bv.z); o.z = o.z > 0.f ? o.z : 0.f;
    o.w = fmaf(ds, acc.w, bv.w); o.w = o.w > 0.f ? o.w : 0.f;
    *(float4*)(Out + (size_t)node * 128 + 4 * l32) = o;
  }
}

// ---- layer-2 aggregate fused with W3 dot: z[node] = relu(dis*agg + b2) . W3 ----

__global__ __launch_bounds__(256) void k_agg_final(const float* __restrict__ H,
                                                   const int* __restrict__ rowptr,
                                                   const EdgeRec* __restrict__ ep,
                                                   const float* __restrict__ dis,
                                                   const float* __restrict__ bias,
                                                   const float* __restrict__ W3,
                                                   float* __restrict__ z, int N) {
  int wave = __builtin_amdgcn_readfirstlane(threadIdx.x >> 6);
  int lane = threadIdx.x & 63;
  int half = lane >> 5;
  int l32  = lane & 31;
  int node = blockIdx.x * 4 + wave;
  if (node >= N) return;
  int beg = rowptr[node], end = rowptr[node + 1];
  int last = end - 1;
  int pmax = (end - beg + 1) >> 1;
  int ebase = beg + half;

  float4 acc = make_float4(0.f, 0.f, 0.f, 0.f);
  EdgeRec cur[4], nxt[4];
#pragma unroll
  for (int j = 0; j < 4; j++) {
    int e = ebase + 2 * j;
    cur[j] = ep[e <= last ? e : last];
  }
  for (int p = 0; p < pmax; p += 4) {
    int nbase = ebase + 2 * (p + 4);
#pragma unroll
    for (int j = 0; j < 4; j++) {
      int e = nbase + 2 * j;
      nxt[j] = ep[e <= last ? e : last];
    }
    float4 h[4];
#pragma unroll
    for (int j = 0; j < 4; j++)
      h[j] = *(const float4*)(H + (size_t)cur[j].x * 128 + 4 * l32);
#pragma unroll
    for (int j = 0; j < 4; j++) {
      int e = ebase + 2 * (p + j);
      float w = (e <= last) ? __int_as_float(cur[j].y) : 0.f;
      acc.x = fmaf(w, h[j].x, acc.x);
      acc.y = fmaf(w, h[j].y, acc.y);
      acc.z = fmaf(w, h[j].z, acc.z);
      acc.w = fmaf(w, h[j].w, acc.w);
    }
#pragma unroll
    for (int j = 0; j < 4; j++) cur[j] = nxt[j];
  }
  acc.x += __shfl_xor(acc.x, 32, 64);
  acc.y += __shfl_xor(acc.y, 32, 64);
  acc.z += __shfl_xor(acc.z, 32, 64);
  acc.w += __shfl_xor(acc.w, 32, 64);
  // both halves now identical; compute o and partial dot in all 64 lanes
  float ds = dis[node];
  float4 bv = *(const float4*)(bias + 4 * l32);
  float4 w3v = *(const float4*)(W3 + 4 * l32);
  float o, pdot = 0.f;
  o = fmaf(ds, acc.x, bv.x); o = o > 0.f ? o : 0.f; pdot = fmaf(o, w3v.x, pdot);
  o = fmaf(ds, acc.y, bv.y); o = o > 0.f ? o : 0.f; pdot = fmaf(o, w3v.y, pdot);
  o = fmaf(ds, acc.z, bv.z); o = o > 0.f ? o : 0.f; pdot = fmaf(o, w3v.z, pdot);
  o = fmaf(ds, acc.w, bv.w); o = o > 0.f ? o : 0.f; pdot = fmaf(o, w3v.w, pdot);
  // 64-lane reduce double-counts (halves identical) -> scale by 0.5
#pragma unroll
  for (int off = 32; off > 0; off >>= 1) pdot += __shfl_down(pdot, off, 64);
  if (lane == 0) z[node] = 0.5f * pdot;
}

// ---------------- scalar aggregate + bias + relu ----------------

__global__ void k_aggs(const float* __restrict__ z, const int* __restrict__ rowptr,
                       const EdgeRec* __restrict__ ep, const float* __restrict__ dis,
                       const float* __restrict__ b3, float* __restrict__ out, int N) {
  int n = blockIdx.x * blockDim.x + threadIdx.x;
  if (n >= N) return;
  float acc = 0.f;
  int end = rowptr[n + 1];
  for (int e = rowptr[n]; e < end; e++) {
    EdgeRec p = ep[e];
    acc = fmaf(__int_as_float(p.y), z[p.x], acc);
  }
  acc = fmaf(dis[n], acc, b3[0]);
  out[n] = acc > 0.f ? acc : 0.f;
}

// ---------------- launch ----------------

extern "C" void kernel_launch(void* const* d_in, const int* in_sizes, int n_in,
                              void* d_out, int out_size, void* d_ws, size_t ws_size,
                              hipStream_t stream) {
  const float* x  = (const float*)d_in[0];
  const int*   ei = (const int*)d_in[1];
  const float* ew = (const float*)d_in[2];
  const float* W1 = (const float*)d_in[3];
  const float* b1 = (const float*)d_in[4];
  const float* W2 = (const float*)d_in[5];
  const float* b2 = (const float*)d_in[6];
  const float* W3 = (const float*)d_in[7];
  const float* b3 = (const float*)d_in[8];
  int N = in_sizes[0] / NFEAT;
  int E = in_sizes[2];
  int M = E + N;
  const int* srcp = ei;
  const int* dstp = ei + E;

  char* p = (char*)d_ws;
  auto carve = [&](size_t bytes) -> void* {
    void* r = (void*)p;
    p += (bytes + 511) & ~(size_t)511;
    return r;
  };
  unsigned long long* packed = (unsigned long long*)carve(sizeof(unsigned long long) * N);
  int*     off    = (int*)  carve(sizeof(int) * E);
  int*     rowptr = (int*)  carve(sizeof(int) * (N + 1));
  float*   dis    = (float*)carve(sizeof(float) * N);
  int*     bsum   = (int*)  carve(sizeof(int) * 1024);
  EdgeRec* ep     = (EdgeRec*)carve(sizeof(EdgeRec) * M);
  float*   t1     = (float*)carve(sizeof(float) * (size_t)N * NFEAT);
  float*   t2     = (float*)carve(sizeof(float) * (size_t)N * NFEAT);
  float*   z      = (float*)carve(sizeof(float) * N);

  int gN = (N + 255) / 256, gE = (E + 255) / 256;
  int SB = (N + 1023) / 1024;

  k_init<<<gN, 256, 0, stream>>>(packed, N);
  k_count64<<<gE, 256, 0, stream>>>(dstp, ew, packed, off, E);
  k_dis<<<gN, 256, 0, stream>>>(packed, dis, N);
  k_scan1<<<SB, 256, 0, stream>>>(packed, bsum, N);
  k_scan2<<<1, 1024, 0, stream>>>(bsum, SB);
  k_scan3<<<SB, 256, 0, stream>>>(packed, bsum, rowptr, N, M);
  k_selfloop<<<gN, 256, 0, stream>>>(rowptr, dis, ep, N);
  k_fill<<<gE, 256, 0, stream>>>(srcp, dstp, ew, dis, rowptr, off, ep, E);

  int numTiles = (N + 63) / 64;   // 64 rows per tile (8 waves x 8 rows)
  int gg = 256;                   // 1 block/CU (128 KB LDS), persistent
  int gW = (N + 3) / 4;

  k_gemm128<<<gg, 512, 0, stream>>>(x, W1, t1, N, numTiles);
  k_agg128<<<gW, 256, 0, stream>>>(t1, rowptr, ep, dis, b1, t2, N);
  k_gemm128<<<gg, 512, 0, stream>>>(t2, W2, t1, N, numTiles);
  k_agg_final<<<gW, 256, 0, stream>>>(t1, rowptr, ep, dis, b2, W3, z, N);
  k_aggs<<<gN, 256, 0, stream>>>(z, rowptr, ep, dis, b3, (float*)d_out, N);
}

// Round 8
// 588.040 us; speedup vs baseline: 1.2295x; 1.0818x over previous
//
#include <hip/hip_runtime.h>
#include <math.h>

#define NFEAT 128

// edge record: .x = col index (int), .y = dis[src]*w (float bits); dis[dst] folded into epilogue
typedef int2 EdgeRec;

// ---------------- CSR build ----------------

__global__ void k_init(unsigned long long* packed, int N) {
  int i = blockIdx.x * blockDim.x + threadIdx.x;
  if (i < N) packed[i] = 0ull;
}

// ONE u64 atomic per edge: count in bits[40..], fixed-point (2^-32) weight sum in bits[0..40).
// Returned old count = this edge's slot offset within its row.
__global__ void k_count64(const int* __restrict__ dst, const float* __restrict__ ew,
                          unsigned long long* packed, int* off, int E) {
  int e = blockIdx.x * blockDim.x + threadIdx.x;
  if (e < E) {
    unsigned long long add = (1ull << 40) | (unsigned long long)(ew[e] * 4294967296.0f);
    unsigned long long old = atomicAdd(&packed[dst[e]], add);
    off[e] = (int)(old >> 40);
  }
}

__global__ void k_dis(const unsigned long long* __restrict__ packed, float* dis, int N) {
  int i = blockIdx.x * blockDim.x + threadIdx.x;
  if (i < N) {
    double s = (double)(packed[i] & ((1ull << 40) - 1)) * 2.3283064365386963e-10;  // /2^32
    float dg = 1.0f + (float)s;  // + self-loop weight
    dis[i] = 1.0f / sqrtf(dg);
  }
}

// ---- 3-phase parallel exclusive scan of (cnt[i]+1) -> rowptr, 1024 elems/block ----

__global__ __launch_bounds__(256) void k_scan1(const unsigned long long* __restrict__ packed,
                                               int* bsum, int N) {
  __shared__ int ls[256];
  int b = blockIdx.x, t = threadIdx.x;
  int base = b * 1024 + t * 4;
  int s = 0;
#pragma unroll
  for (int j = 0; j < 4; j++) { int i = base + j; if (i < N) s += (int)(packed[i] >> 40) + 1; }
  ls[t] = s;
  __syncthreads();
  for (int off = 128; off > 0; off >>= 1) {
    if (t < off) ls[t] += ls[t + off];
    __syncthreads();
  }
  if (t == 0) bsum[b] = ls[0];
}

__global__ __launch_bounds__(1024) void k_scan2(int* bsum, int SB) {
  __shared__ int ls[1024];
  int t = threadIdx.x;
  int v = (t < SB) ? bsum[t] : 0;
  ls[t] = v;
  __syncthreads();
  for (int off = 1; off < 1024; off <<= 1) {
    int u = (t >= off) ? ls[t - off] : 0;
    __syncthreads();
    ls[t] += u;
    __syncthreads();
  }
  if (t < SB) bsum[t] = ls[t] - v;  // exclusive
}

__global__ __launch_bounds__(256) void k_scan3(const unsigned long long* __restrict__ packed,
                                               const int* __restrict__ bsum,
                                               int* rowptr, int N, int M) {
  __shared__ int ls[256];
  int b = blockIdx.x, t = threadIdx.x;
  int base = b * 1024 + t * 4;
  int v[4]; int s = 0;
#pragma unroll
  for (int j = 0; j < 4; j++) {
    int i = base + j;
    v[j] = (i < N) ? (int)(packed[i] >> 40) + 1 : 0;
    s += v[j];
  }
  ls[t] = s;
  __syncthreads();
  for (int off = 1; off < 256; off <<= 1) {
    int u = (t >= off) ? ls[t - off] : 0;
    __syncthreads();
    ls[t] += u;
    __syncthreads();
  }
  int run = bsum[b] + ls[t] - s;
#pragma unroll
  for (int j = 0; j < 4; j++) { int i = base + j; if (i < N) { rowptr[i] = run; run += v[j]; } }
  if (b == 0 && t == 0) rowptr[N] = M;
}

__global__ void k_selfloop(const int* __restrict__ rowptr, const float* __restrict__ dis,
                           EdgeRec* ep, int N) {
  int i = blockIdx.x * blockDim.x + threadIdx.x;
  if (i < N) {
    EdgeRec r; r.x = i; r.y = __float_as_int(dis[i]);  // dis[i]*1.0; *dis[i] applied in epilogue
    ep[rowptr[i]] = r;
  }
}

// no atomics: slot = rowptr[dst] + 1 + off[e]
__global__ void k_fill(const int* __restrict__ src, const int* __restrict__ dst,
                       const float* __restrict__ ew, const float* __restrict__ dis,
                       const int* __restrict__ rowptr, const int* __restrict__ off,
                       EdgeRec* ep, int E) {
  int e = blockIdx.x * blockDim.x + threadIdx.x;
  if (e < E) {
    int s = src[e], d = dst[e];
    int p = rowptr[d] + 1 + off[e];
    EdgeRec r; r.x = s; r.y = __float_as_int(dis[s] * ew[e]);
    ep[p] = r;
  }
}

// ---------------- dense GEMM: Y[N,128] = X[N,128] @ W[128,128] ----------------
// Register-blocked, LDS-instruction-minimal. 512 threads (8 waves), 1 block/CU.
// LDS: W 64 KB + X tile (128 rows) 64 KB. Lane owns 8 rows x 4 cols (32 accs).
// Per k-group-of-4 per wave: 8 lane-distinct x b128 reads (XOR k-swizzle spreads
// the 8 lr-groups over disjoint 4-bank spans -> conflict-free) + 4 w b128 reads
// = 12 LDS instrs per 128 lane-FMAs (2x the FMA:LDS ratio of the previous kernel).

__global__ __launch_bounds__(512, 2) void k_gemm128(const float* __restrict__ X,
                                                    const float* __restrict__ W,
                                                    float* __restrict__ Y,
                                                    int N, int numTiles) {
  __shared__ float sW[128 * 128];  // 64 KB, [k][c] row-major
  __shared__ float sX[128 * 128];  // 64 KB, [r][k^swz(r)] swizzled
  int t = threadIdx.x;
  int wave = __builtin_amdgcn_readfirstlane(t >> 6);  // 0..7
  int lane = t & 63;
  int lr = (lane >> 3) & 7;  // row group within wave
  int lc = lane & 7;         // col group within wave
  int wr = wave >> 2;        // 0..1: row half
  int wc = wave & 3;         // 0..3: col quarter

  {
    const float4* W4 = (const float4*)W;
    float4* sW4 = (float4*)sW;
    for (int i = t; i < 4096; i += 512) sW4[i] = W4[i];
  }

  const float4* X4 = (const float4*)X;
  int grmax = N - 1;
  int r0 = wr * 64 + lr * 8;   // wave/lane row base within tile
  int c0 = wc * 32 + lc * 4;   // wave/lane col base
  int swzk = lr << 2;          // k-swizzle for this lane's rows

  for (int tile = blockIdx.x; tile < numTiles; tile += gridDim.x) {
    int rowBase = tile * 128;
    __syncthreads();  // prior tile's reads of sX done
    {
      int kg = t & 31;   // k-group 0..31
      int rb = t >> 5;   // 0..15
#pragma unroll
      for (int p = 0; p < 8; p++) {
        int r = rb + 16 * p;
        int gr = rowBase + r; if (gr > grmax) gr = grmax;
        float4 v = X4[(size_t)gr * 32 + kg];
        int swz = ((r >> 3) & 7) << 2;
        *(float4*)(&sX[r * 128 + ((kg * 4) ^ swz)]) = v;
      }
    }
    __syncthreads();

    float4 acc[8];
#pragma unroll
    for (int i = 0; i < 8; i++) acc[i] = make_float4(0.f, 0.f, 0.f, 0.f);

#pragma unroll 1
    for (int kg = 0; kg < 32; kg++) {
      int kk0 = kg * 4;
      float4 xf[8];
#pragma unroll
      for (int i = 0; i < 8; i++)
        xf[i] = *(const float4*)(&sX[(r0 + i) * 128 + (kk0 ^ swzk)]);
      float4 wf[4];
#pragma unroll
      for (int kk = 0; kk < 4; kk++)
        wf[kk] = *(const float4*)(&sW[(kk0 + kk) * 128 + c0]);
#pragma unroll
      for (int kk = 0; kk < 4; kk++) {
#pragma unroll
        for (int i = 0; i < 8; i++) {
          float xs = (&xf[i].x)[kk];
          acc[i].x = fmaf(xs, wf[kk].x, acc[i].x);
          acc[i].y = fmaf(xs, wf[kk].y, acc[i].y);
          acc[i].z = fmaf(xs, wf[kk].z, acc[i].z);
          acc[i].w = fmaf(xs, wf[kk].w, acc[i].w);
        }
      }
    }
#pragma unroll
    for (int i = 0; i < 8; i++) {
      int row = rowBase + r0 + i;
      if (row < N)
        *(float4*)(Y + (size_t)row * 128 + c0) = acc[i];
    }
  }
}

// ---------------- sparse aggregate, 128-wide: Out = relu(dis[n]*agg + b) ----------------
// One wave per dst node. Half-wave split: lanes 0-31 take even edge slots, 32-63 odd.
// Lane gathers float4 (features 4*l32..+3); ep records for next group prefetched.

__global__ __launch_bounds__(256) void k_agg128(const float* __restrict__ H,
                                                const int* __restrict__ rowptr,
                                                const EdgeRec* __restrict__ ep,
                                                const float* __restrict__ dis,
                                                const float* __restrict__ bias,
                                                float* __restrict__ Out, int N) {
  int wave = __builtin_amdgcn_readfirstlane(threadIdx.x >> 6);
  int lane = threadIdx.x & 63;
  int half = lane >> 5;
  int l32  = lane & 31;
  int node = blockIdx.x * 4 + wave;
  if (node >= N) return;
  int beg = rowptr[node], end = rowptr[node + 1];
  int last = end - 1;
  int pmax = (end - beg + 1) >> 1;  // pair-slots; slot p covers edge beg+2p+half
  int ebase = beg + half;

  float4 acc = make_float4(0.f, 0.f, 0.f, 0.f);
  EdgeRec cur[4], nxt[4];
#pragma unroll
  for (int j = 0; j < 4; j++) {
    int e = ebase + 2 * j;
    cur[j] = ep[e <= last ? e : last];
  }
  for (int p = 0; p < pmax; p += 4) {
    int nbase = ebase + 2 * (p + 4);
#pragma unroll
    for (int j = 0; j < 4; j++) {
      int e = nbase + 2 * j;
      nxt[j] = ep[e <= last ? e : last];
    }
    float4 h[4];
#pragma unroll
    for (int j = 0; j < 4; j++)
      h[j] = *(const float4*)(H + (size_t)cur[j].x * 128 + 4 * l32);
#pragma unroll
    for (int j = 0; j < 4; j++) {
      int e = ebase + 2 * (p + j);
      float w = (e <= last) ? __int_as_float(cur[j].y) : 0.f;
      acc.x = fmaf(w, h[j].x, acc.x);
      acc.y = fmaf(w, h[j].y, acc.y);
      acc.z = fmaf(w, h[j].z, acc.z);
      acc.w = fmaf(w, h[j].w, acc.w);
    }
#pragma unroll
    for (int j = 0; j < 4; j++) cur[j] = nxt[j];
  }
  // combine halves
  acc.x += __shfl_xor(acc.x, 32, 64);
  acc.y += __shfl_xor(acc.y, 32, 64);
  acc.z += __shfl_xor(acc.z, 32, 64);
  acc.w += __shfl_xor(acc.w, 32, 64);
  if (half == 0) {
    float ds = dis[node];
    float4 bv = *(const float4*)(bias + 4 * l32);
    float4 o;
    o.x = fmaf(ds, acc.x, bv.x); o.x = o.x > 0.f ? o.x : 0.f;
    o.y = fmaf(ds, acc.y, bv.y); o.y = o.y > 0.f ? o.y : 0.f;
    o.z = fmaf(ds, acc.z, bv.z); o.z = o.z > 0.f ? o.z : 0.f;
    o.w = fmaf(ds, acc.w, bv.w); o.w = o.w > 0.f ? o.w : 0.f;
    *(float4*)(Out + (size_t)node * 128 + 4 * l32) = o;
  }
}

// ---- layer-2 aggregate fused with W3 dot: z[node] = relu(dis*agg + b2) . W3 ----

__global__ __launch_bounds__(256) void k_agg_final(const float* __restrict__ H,
                                                   const int* __restrict__ rowptr,
                                                   const EdgeRec* __restrict__ ep,
                                                   const float* __restrict__ dis,
                                                   const float* __restrict__ bias,
                                                   const float* __restrict__ W3,
                                                   float* __restrict__ z, int N) {
  int wave = __builtin_amdgcn_readfirstlane(threadIdx.x >> 6);
  int lane = threadIdx.x & 63;
  int half = lane >> 5;
  int l32  = lane & 31;
  int node = blockIdx.x * 4 + wave;
  if (node >= N) return;
  int beg = rowptr[node], end = rowptr[node + 1];
  int last = end - 1;
  int pmax = (end - beg + 1) >> 1;
  int ebase = beg + half;

  float4 acc = make_float4(0.f, 0.f, 0.f, 0.f);
  EdgeRec cur[4], nxt[4];
#pragma unroll
  for (int j = 0; j < 4; j++) {
    int e = ebase + 2 * j;
    cur[j] = ep[e <= last ? e : last];
  }
  for (int p = 0; p < pmax; p += 4) {
    int nbase = ebase + 2 * (p + 4);
#pragma unroll
    for (int j = 0; j < 4; j++) {
      int e = nbase + 2 * j;
      nxt[j] = ep[e <= last ? e : last];
    }
    float4 h[4];
#pragma unroll
    for (int j = 0; j < 4; j++)
      h[j] = *(const float4*)(H + (size_t)cur[j].x * 128 + 4 * l32);
#pragma unroll
    for (int j = 0; j < 4; j++) {
      int e = ebase + 2 * (p + j);
      float w = (e <= last) ? __int_as_float(cur[j].y) : 0.f;
      acc.x = fmaf(w, h[j].x, acc.x);
      acc.y = fmaf(w, h[j].y, acc.y);
      acc.z = fmaf(w, h[j].z, acc.z);
      acc.w = fmaf(w, h[j].w, acc.w);
    }
#pragma unroll
    for (int j = 0; j < 4; j++) cur[j] = nxt[j];
  }
  acc.x += __shfl_xor(acc.x, 32, 64);
  acc.y += __shfl_xor(acc.y, 32, 64);
  acc.z += __shfl_xor(acc.z, 32, 64);
  acc.w += __shfl_xor(acc.w, 32, 64);
  // both halves now identical; compute o and partial dot in all 64 lanes
  float ds = dis[node];
  float4 bv = *(const float4*)(bias + 4 * l32);
  float4 w3v = *(const float4*)(W3 + 4 * l32);
  float o, pdot = 0.f;
  o = fmaf(ds, acc.x, bv.x); o = o > 0.f ? o : 0.f; pdot = fmaf(o, w3v.x, pdot);
  o = fmaf(ds, acc.y, bv.y); o = o > 0.f ? o : 0.f; pdot = fmaf(o, w3v.y, pdot);
  o = fmaf(ds, acc.z, bv.z); o = o > 0.f ? o : 0.f; pdot = fmaf(o, w3v.z, pdot);
  o = fmaf(ds, acc.w, bv.w); o = o > 0.f ? o : 0.f; pdot = fmaf(o, w3v.w, pdot);
  // 64-lane reduce double-counts (halves identical) -> scale by 0.5
#pragma unroll
  for (int off = 32; off > 0; off >>= 1) pdot += __shfl_down(pdot, off, 64);
  if (lane == 0) z[node] = 0.5f * pdot;
}

// ---------------- scalar aggregate + bias + relu ----------------

__global__ void k_aggs(const float* __restrict__ z, const int* __restrict__ rowptr,
                       const EdgeRec* __restrict__ ep, const float* __restrict__ dis,
                       const float* __restrict__ b3, float* __restrict__ out, int N) {
  int n = blockIdx.x * blockDim.x + threadIdx.x;
  if (n >= N) return;
  float acc = 0.f;
  int end = rowptr[n + 1];
  for (int e = rowptr[n]; e < end; e++) {
    EdgeRec p = ep[e];
    acc = fmaf(__int_as_float(p.y), z[p.x], acc);
  }
  acc = fmaf(dis[n], acc, b3[0]);
  out[n] = acc > 0.f ? acc : 0.f;
}

// ---------------- launch ----------------

extern "C" void kernel_launch(void* const* d_in, const int* in_sizes, int n_in,
                              void* d_out, int out_size, void* d_ws, size_t ws_size,
                              hipStream_t stream) {
  const float* x  = (const float*)d_in[0];
  const int*   ei = (const int*)d_in[1];
  const float* ew = (const float*)d_in[2];
  const float* W1 = (const float*)d_in[3];
  const float* b1 = (const float*)d_in[4];
  const float* W2 = (const float*)d_in[5];
  const float* b2 = (const float*)d_in[6];
  const float* W3 = (const float*)d_in[7];
  const float* b3 = (const float*)d_in[8];
  int N = in_sizes[0] / NFEAT;
  int E = in_sizes[2];
  int M = E + N;
  const int* srcp = ei;
  const int* dstp = ei + E;

  char* p = (char*)d_ws;
  auto carve = [&](size_t bytes) -> void* {
    void* r = (void*)p;
    p += (bytes + 511) & ~(size_t)511;
    return r;
  };
  unsigned long long* packed = (unsigned long long*)carve(sizeof(unsigned long long) * N);
  int*     off    = (int*)  carve(sizeof(int) * E);
  int*     rowptr = (int*)  carve(sizeof(int) * (N + 1));
  float*   dis    = (float*)carve(sizeof(float) * N);
  int*     bsum   = (int*)  carve(sizeof(int) * 1024);
  EdgeRec* ep     = (EdgeRec*)carve(sizeof(EdgeRec) * M);
  float*   t1     = (float*)carve(sizeof(float) * (size_t)N * NFEAT);
  float*   t2     = (float*)carve(sizeof(float) * (size_t)N * NFEAT);
  float*   z      = (float*)carve(sizeof(float) * N);

  int gN = (N + 255) / 256, gE = (E + 255) / 256;
  int SB = (N + 1023) / 1024;

  k_init<<<gN, 256, 0, stream>>>(packed, N);
  k_count64<<<gE, 256, 0, stream>>>(dstp, ew, packed, off, E);
  k_dis<<<gN, 256, 0, stream>>>(packed, dis, N);
  k_scan1<<<SB, 256, 0, stream>>>(packed, bsum, N);
  k_scan2<<<1, 1024, 0, stream>>>(bsum, SB);
  k_scan3<<<SB, 256, 0, stream>>>(packed, bsum, rowptr, N, M);
  k_selfloop<<<gN, 256, 0, stream>>>(rowptr, dis, ep, N);
  k_fill<<<gE, 256, 0, stream>>>(srcp, dstp, ew, dis, rowptr, off, ep, E);

  int numTiles = (N + 127) / 128;  // 128 rows per tile
  int gg = 256;                    // 1 block/CU, persistent
  int gW = (N + 3) / 4;

  k_gemm128<<<gg, 512, 0, stream>>>(x, W1, t1, N, numTiles);
  k_agg128<<<gW, 256, 0, stream>>>(t1, rowptr, ep, dis, b1, t2, N);
  k_gemm128<<<gg, 512, 0, stream>>>(t2, W2, t1, N, numTiles);
  k_agg_final<<<gW, 256, 0, stream>>>(t1, rowptr, ep, dis, b2, W3, z, N);
  k_aggs<<<gN, 256, 0, stream>>>(z, rowptr, ep, dis, b3, (float*)d_out, N);
}